// Round 12
// baseline (279.283 us; speedup 1.0000x reference)
//
#include <hip/hip_runtime.h>

// LSTMModel: B=4096, T=512, IN=2, H=12, OUT=2, fp32.
// r12: TWO batch elements per wave64 (f2 = {elemA, elemB}).
// lane = unit*4 + gate (48 active); 512 blocks x 256 thr -> 2048 waves = 2/SIMD.
// Rationale (closes r4-r11 plateau arithmetic): v_pk_fma_f32 is HALF-RATE
// (packing never saved VALU-pipe cycles), and the DS pipe was ~88% busy at
// 16 waves/CU x 13 DS ops (the broadcast h-reads pay full bandwidth). With
// 2 elems/wave the SAME 12 ds_read_b64 serve 2 elements -> DS/elem halved;
// weights (dup'd f2) and x/loop overhead also amortize 2x.
// Straight per-layer updates with 1-instr mov_dpp quad gathers.

namespace {
constexpr int H  = 12;
constexpr int T  = 512;
constexpr float LOG2E = 1.4426950408889634f;

typedef float f2 __attribute__((ext_vector_type(2)));

__device__ __forceinline__ f2 fma2(f2 a, f2 b, f2 c) {
    return __builtin_elementwise_fma(a, b, c);
}
__device__ __forceinline__ float exp2_(float x) {
    float r; asm("v_exp_f32 %0, %1" : "=v"(r) : "v"(x)); return r;
}
__device__ __forceinline__ float rcp_(float x) { return __builtin_amdgcn_rcpf(x); }
__device__ __forceinline__ void memfence_() { asm volatile("" ::: "memory"); }
__device__ __forceinline__ f2 dup(float v) { f2 d; d.x = v; d.y = v; return d; }

// single-instruction DPP mov (old = undef, bound_ctrl=1)
template <int CTRL>
__device__ __forceinline__ float mdpp(float v) {
    return __int_as_float(__builtin_amdgcn_mov_dpp(
        __float_as_int(v), CTRL, 0xF, 0xF, true));
}
constexpr int BC1 = 0x55;  // quad broadcast lane1 -> f
constexpr int BC2 = 0xAA;  // quad broadcast lane2 -> g
constexpr int BC3 = 0xFF;  // quad broadcast lane3 -> o
} // namespace

__global__
__attribute__((amdgpu_flat_work_group_size(256, 256)))
__attribute__((amdgpu_waves_per_eu(2, 2)))
void lstm2_fc_kernel(
    const float* __restrict__ x,      // (4096, 512, 2)
    const float* __restrict__ W_ih0,  // (48, 2)
    const float* __restrict__ W_hh0,  // (48, 12)
    const float* __restrict__ b_ih0,  // (48)
    const float* __restrict__ b_hh0,  // (48)
    const float* __restrict__ W_ih1,  // (48, 12)
    const float* __restrict__ W_hh1,  // (48, 12)
    const float* __restrict__ b_ih1,  // (48)
    const float* __restrict__ b_hh1,  // (48)
    const float* __restrict__ fc_W,   // (2, 12)
    const float* __restrict__ fc_b,   // (2)
    float* __restrict__ out)          // (4096, 2)
{
    const int lane = threadIdx.x & 63;
    const int wid  = __builtin_amdgcn_readfirstlane((int)threadIdx.x >> 6);
    const int bA   = blockIdx.x * 8 + wid * 2;   // elements bA, bA+1
    const int u    = lane >> 2;                  // unit 0..15 (12 active)
    const int gate = lane & 3;                   // 0:i 1:f 2:g 3:o
    const int uc   = (u < H) ? u : 0;
    const int r    = gate * H + uc;              // weight row

    const float pre  = (gate == 2) ? 2.0f : 1.0f;
    const float kmul = -LOG2E * pre;             // exp2 prescale folded in
    const float pa   = 1.0f - pre;
    const float km2  = -2.0f * LOG2E;

    // ---- per-wave LDS: h0 pairs at [0..23], h1 pairs at [24..47] ----
    __shared__ __align__(16) float sm[4 * 64];
    float* smb = &sm[wid * 64];
    const bool pub = (gate == 0) && (u < H);
    float* smw0 = smb + 2 * uc;                  // f2 slot for (h0A, h0B)
    float* smw1 = smb + 24 + 2 * uc;             // f2 slot for (h1A, h1B)

    // ---------------- dup'd prescaled weights -> registers ----------------
    const f2 wx0 = dup(kmul * W_ih0[r * 2 + 0]);
    const f2 wx1 = dup(kmul * W_ih0[r * 2 + 1]);
    f2 whh0[H], wih1[H], whh1[H];
#pragma unroll
    for (int j = 0; j < H; ++j) {
        whh0[j] = dup(kmul * W_hh0[r * H + j]);
        wih1[j] = dup(kmul * W_ih1[r * H + j]);
        whh1[j] = dup(kmul * W_hh1[r * H + j]);
    }
    const f2 b0 = dup(kmul * (b_ih0[r] + b_hh0[r]));
    const f2 b1 = dup(kmul * (b_ih1[r] + b_hh1[r]));

    // ---------------- state ----------------
    f2 c0 = dup(0.0f), c1 = dup(0.0f);
    f2 hp0[H], hq1[H];
#pragma unroll
    for (int j = 0; j < H; ++j) { hp0[j] = dup(0.0f); hq1[j] = dup(0.0f); }

    const float* xpA = x + (size_t)bA * T * 2;
    const float* xpB = xpA + T * 2;              // element bA+1
    float2 xA = *(const float2*)xpA;
    float2 xB = *(const float2*)xpB;

    for (int t = 0; t < T; ++t) {
        const int tn = (t < T - 1) ? (t + 1) : t;
        const float2 xAn = *(const float2*)(xpA + 2 * tn);
        const float2 xBn = *(const float2*)(xpB + 2 * tn);
        f2 px0; px0.x = xA.x; px0.y = xB.x;      // x[.,t,0] for A,B
        f2 px1; px1.x = xA.y; px1.y = xB.y;      // x[.,t,1]

        // ---- layer-0 dot: 14 terms, 3 chains ----
        f2 aA = fma2(wx0, px0, b0);
        aA = fma2(wx1, px1, aA);
        aA = fma2(whh0[0], hp0[0], aA);
        aA = fma2(whh0[1], hp0[1], aA);
        f2 aB = whh0[2] * hp0[2];
        aB = fma2(whh0[3], hp0[3], aB);
        aB = fma2(whh0[4], hp0[4], aB);
        aB = fma2(whh0[5], hp0[5], aB);
        f2 aC = whh0[6] * hp0[6];
        aC = fma2(whh0[7], hp0[7], aC);
        aC = fma2(whh0[8], hp0[8], aC);
        aC = fma2(whh0[9], hp0[9], aC);
        aA = aA + aB + aC;
        aA = fma2(whh0[10], hp0[10], aA);
        aA = fma2(whh0[11], hp0[11], aA);
        // activation (per-half scalar; pipe cost == packed)
        f2 s;
        s.x = fmaf(pre, rcp_(1.0f + exp2_(aA.x)), pa);
        s.y = fmaf(pre, rcp_(1.0f + exp2_(aA.y)), pa);
        // quad gathers (valid on gate-0 lanes)
        f2 fB, gB, oB;
        fB.x = mdpp<BC1>(s.x); fB.y = mdpp<BC1>(s.y);
        gB.x = mdpp<BC2>(s.x); gB.y = mdpp<BC2>(s.y);
        oB.x = mdpp<BC3>(s.x); oB.y = mdpp<BC3>(s.y);
        c0 = fma2(fB, c0, s * gB);               // c0(t) on gate-0 lanes
        f2 th;
        th.x = fmaf(2.0f, rcp_(1.0f + exp2_(km2 * c0.x)), -1.0f);
        th.y = fmaf(2.0f, rcp_(1.0f + exp2_(km2 * c0.y)), -1.0f);
        const f2 h0v = oB * th;
        if (pub) *(f2*)smw0 = h0v;               // publish (h0A,h0B)
        memfence_();
        // broadcast readback: h0(t) and h1(t-1), 12 x ds_read_b64
#pragma unroll
        for (int j = 0; j < H; ++j) hp0[j] = *(const f2*)(smb + 2 * j);
#pragma unroll
        for (int j = 0; j < H; ++j) hq1[j] = *(const f2*)(smb + 24 + 2 * j);

        // ---- layer-1 dot: 24 terms, 3 chains ----
        f2 dA = fma2(wih1[0], hp0[0], b1);
        dA = fma2(whh1[0], hq1[0], dA);
        dA = fma2(wih1[1], hp0[1], dA);
        dA = fma2(whh1[1], hq1[1], dA);
        dA = fma2(wih1[2], hp0[2], dA);
        dA = fma2(whh1[2], hq1[2], dA);
        dA = fma2(wih1[3], hp0[3], dA);
        dA = fma2(whh1[3], hq1[3], dA);
        f2 dB = wih1[4] * hp0[4];
        dB = fma2(whh1[4], hq1[4], dB);
        dB = fma2(wih1[5], hp0[5], dB);
        dB = fma2(whh1[5], hq1[5], dB);
        dB = fma2(wih1[6], hp0[6], dB);
        dB = fma2(whh1[6], hq1[6], dB);
        dB = fma2(wih1[7], hp0[7], dB);
        dB = fma2(whh1[7], hq1[7], dB);
        f2 dC = wih1[8] * hp0[8];
        dC = fma2(whh1[8], hq1[8], dC);
        dC = fma2(wih1[9], hp0[9], dC);
        dC = fma2(whh1[9], hq1[9], dC);
        dC = fma2(wih1[10], hp0[10], dC);
        dC = fma2(whh1[10], hq1[10], dC);
        dC = fma2(wih1[11], hp0[11], dC);
        dC = fma2(whh1[11], hq1[11], dC);
        dA = dA + dB + dC;
        f2 s1;
        s1.x = fmaf(pre, rcp_(1.0f + exp2_(dA.x)), pa);
        s1.y = fmaf(pre, rcp_(1.0f + exp2_(dA.y)), pa);
        fB.x = mdpp<BC1>(s1.x); fB.y = mdpp<BC1>(s1.y);
        gB.x = mdpp<BC2>(s1.x); gB.y = mdpp<BC2>(s1.y);
        oB.x = mdpp<BC3>(s1.x); oB.y = mdpp<BC3>(s1.y);
        c1 = fma2(fB, c1, s1 * gB);
        th.x = fmaf(2.0f, rcp_(1.0f + exp2_(km2 * c1.x)), -1.0f);
        th.y = fmaf(2.0f, rcp_(1.0f + exp2_(km2 * c1.y)), -1.0f);
        const f2 h1v = oB * th;
        memfence_();                             // keep hq1 reads above this write
        if (pub) *(f2*)smw1 = h1v;               // publish (h1A,h1B)

        xA = xAn; xB = xBn;
    }

    // ---------------- final FC (lane 0 of each wave) ----------------
    memfence_();
#pragma unroll
    for (int j = 0; j < H; ++j) hq1[j] = *(const f2*)(smb + 24 + 2 * j);
    if (lane == 0) {
        f2 acc0 = dup(fc_b[0]);
        f2 acc1 = dup(fc_b[1]);
#pragma unroll
        for (int j = 0; j < H; ++j) {
            acc0 = fma2(dup(fc_W[j]),     hq1[j], acc0);
            acc1 = fma2(dup(fc_W[H + j]), hq1[j], acc1);
        }
        out[(size_t)bA * 2 + 0] = acc0.x;
        out[(size_t)bA * 2 + 1] = acc1.x;
        out[(size_t)(bA + 1) * 2 + 0] = acc0.y;
        out[(size_t)(bA + 1) * 2 + 1] = acc1.y;
    }
}

extern "C" void kernel_launch(void* const* d_in, const int* in_sizes, int n_in,
                              void* d_out, int out_size, void* d_ws, size_t ws_size,
                              hipStream_t stream) {
    const float* x     = (const float*)d_in[0];
    const float* W_ih0 = (const float*)d_in[1];
    const float* W_hh0 = (const float*)d_in[2];
    const float* b_ih0 = (const float*)d_in[3];
    const float* b_hh0 = (const float*)d_in[4];
    const float* W_ih1 = (const float*)d_in[5];
    const float* W_hh1 = (const float*)d_in[6];
    const float* b_ih1 = (const float*)d_in[7];
    const float* b_hh1 = (const float*)d_in[8];
    const float* fc_W  = (const float*)d_in[9];
    const float* fc_b  = (const float*)d_in[10];
    float* out = (float*)d_out;

    // 4096 elements, 2 per wave, 4 waves per block -> 512 blocks (2 blocks/CU)
    lstm2_fc_kernel<<<512, 256, 0, stream>>>(
        x, W_ih0, W_hh0, b_ih0, b_hh0,
        W_ih1, W_hh1, b_ih1, b_hh1, fc_W, fc_b, out);
}